// Round 1
// 1356.365 us; speedup vs baseline: 1.0109x; 1.0109x over previous
//
#include <hip/hip_runtime.h>
#include <cstddef>
#include <cstdint>

// ---------------------------------------------------------------------------
// N=50000 nodes, E=1,650,000 edges (incl. self loops). Stages (in,out):
// (512,384),(384,256),(256,128), FC 128->128.
// Pipeline (all activations/weights fp16, accumulation fp32):
//   convert -> [per stage: MFMA GEMM -> CSR agg] x6 -> MFMA FC (fp32 out)
// GEMM-first restructuring: (A h) W^T == A (h W^T); row scales commute.
// R1: agg unrolled 4 edges deep (12/8/4 loads in flight) to fix the
//     latency-bound gather; hgemm staged via global_load_lds width=16.
// ---------------------------------------------------------------------------

typedef _Float16 h8 __attribute__((ext_vector_type(8)));
typedef _Float16 h4 __attribute__((ext_vector_type(4)));
typedef float f32x4 __attribute__((ext_vector_type(4)));

// ---------------- degree / CSR build ----------------

__global__ __launch_bounds__(256) void deg_kernel(
    const int* __restrict__ src, const int* __restrict__ dst,
    int* __restrict__ in_deg, int* __restrict__ out_deg, int E) {
  int e = blockIdx.x * 256 + threadIdx.x;
  if (e < E) {
    atomicAdd(&in_deg[dst[e]], 1);
    atomicAdd(&out_deg[src[e]], 1);
  }
}

__global__ __launch_bounds__(1024) void scan_kernel(
    const int* __restrict__ deg, int* __restrict__ row_ptr, int n) {
  __shared__ int buf[1024];
  __shared__ int carry_s;
  if (threadIdx.x == 0) carry_s = 0;
  __syncthreads();
  for (int base = 0; base < n; base += 1024) {
    int i = base + (int)threadIdx.x;
    int v = (i < n) ? deg[i] : 0;
    buf[threadIdx.x] = v;
    __syncthreads();
    #pragma unroll
    for (int off = 1; off < 1024; off <<= 1) {
      int t = 0;
      if ((int)threadIdx.x >= off) t = buf[threadIdx.x - off];
      __syncthreads();
      buf[threadIdx.x] += t;
      __syncthreads();
    }
    int incl  = buf[threadIdx.x];
    int carry = carry_s;
    int total = buf[1023];
    __syncthreads();
    if (i < n) row_ptr[i] = carry + incl - v;
    if (threadIdx.x == 0) carry_s = carry + total;
    __syncthreads();
  }
  if (threadIdx.x == 0) row_ptr[n] = carry_s;
}

__global__ __launch_bounds__(256) void scatter_kernel(
    const int* __restrict__ src, const int* __restrict__ dst,
    const int* __restrict__ row_ptr, int* __restrict__ cnt,
    int* __restrict__ csr, int E) {
  int e = blockIdx.x * 256 + threadIdx.x;
  if (e < E) {
    int d = dst[e];
    int pos = row_ptr[d] + atomicAdd(&cnt[d], 1);
    csr[pos] = src[e];
  }
}

__global__ __launch_bounds__(256) void scaler_kernel(
    const int* __restrict__ in_deg, const int* __restrict__ out_deg,
    float* __restrict__ inv_src, float* __restrict__ inv_dst,
    float* __restrict__ inv_den, int n) {
  int i = blockIdx.x * 256 + threadIdx.x;
  if (i < n) {
    float od = (float)out_deg[i];
    float id = (float)in_deg[i];
    inv_src[i] = rsqrtf(od > 0.f ? od : 1.0f);
    inv_dst[i] = rsqrtf(id > 0.f ? id : 1.0f);
    inv_den[i] = 1.0f / (id + 1.0f);
  }
}

// ---------------- fp32 -> fp16 conversion (pad region zeroed) ----------------

__global__ __launch_bounds__(256) void cvt_kernel(
    const float* __restrict__ in, _Float16* __restrict__ out,
    long n_in, long n_pad) {
  long i = ((long)blockIdx.x * 256 + (long)threadIdx.x) * 4;
  if (i >= n_pad) return;
  float4 v = (i < n_in) ? *(const float4*)(in + i) : make_float4(0.f, 0.f, 0.f, 0.f);
  h4 h = {(_Float16)v.x, (_Float16)v.y, (_Float16)v.z, (_Float16)v.w};
  *(h4*)(out + i) = h;
}

// ---------------- async global->LDS helper (width=16, literal per guide) ----

__device__ __forceinline__ void gload_lds16(const _Float16* g, _Float16* l) {
  __builtin_amdgcn_global_load_lds(
      (const __attribute__((address_space(1))) void*)g,
      (__attribute__((address_space(3))) void*)l, 16, 0, 0);
}

// ---------------- fp16 MFMA GEMM: C[M x Nc] = A[M x K] @ W^T ----------------
// A padded to a multiple of 128 rows (pad rows hold finite junk; their C rows
// are discarded by the m<Mstore store guard). W row-major [Nc x K]. Epilogue:
// optional per-row scale + bias. 256 thr = 4 waves (2x2), 64x64/wave,
// 16x16x32_f16 MFMA, BK=32, LDS 2x8KB.
// Staging: LDS element offset == tid*8 (byte tid*16) -> linear in lane order,
// satisfying global_load_lds' wave-uniform-base + lane*16 destination rule.
// Fragment layouts (HW-verified, guide §3): A/B lane l: idx=l&15, k=(l>>4)*8+j;
// C/D lane l: col=l&15, row=(l>>4)*4+reg.

template <typename OutT>
__global__ __launch_bounds__(256) void hgemm(
    const _Float16* __restrict__ A, const _Float16* __restrict__ W,
    OutT* __restrict__ C, int Mstore, int K, int Nc,
    const float* __restrict__ row_scale, const float* __restrict__ bias) {
  __shared__ _Float16 As[128 * 32];
  __shared__ _Float16 Bs[128 * 32];
  const int tid = threadIdx.x;
  const int bm = blockIdx.x * 128, bn = blockIdx.y * 128;
  const int wave = tid >> 6, lane = tid & 63;
  const int wm = (wave & 1) * 64, wn = (wave >> 1) * 64;
  const int lrow = lane & 15, lq = lane >> 4;

  // staging: thread tid covers row tid>>2, 8 halves at col (tid&3)*8;
  // second chunk is row+64 same col.
  const int r0 = tid >> 2;
  const int cc = (tid & 3) * 8;
  const _Float16* Ag = A + (size_t)(bm + r0) * K + cc;
  const _Float16* Wg = W + (size_t)(bn + r0) * K + cc;
  const size_t rs64 = (size_t)64 * K;
  _Float16* As0 = As + tid * 8;
  _Float16* As1 = As + 64 * 32 + tid * 8;
  _Float16* Bs0 = Bs + tid * 8;
  _Float16* Bs1 = Bs + 64 * 32 + tid * 8;

  f32x4 acc[4][4];
  #pragma unroll
  for (int i = 0; i < 4; ++i)
    #pragma unroll
    for (int j = 0; j < 4; ++j) acc[i][j] = (f32x4){0.f, 0.f, 0.f, 0.f};

  for (int k0 = 0; k0 < K; k0 += 32) {
    __syncthreads();  // previous tile's ds_reads complete before overwrite
    gload_lds16(Ag + k0, As0);
    gload_lds16(Ag + rs64 + k0, As1);
    gload_lds16(Wg + k0, Bs0);
    gload_lds16(Wg + rs64 + k0, Bs1);
    __syncthreads();  // compiler drains vmcnt(0) before s_barrier -> LDS ready
    h8 af[4], bf[4];
    #pragma unroll
    for (int i = 0; i < 4; ++i)
      af[i] = *(const h8*)(As + (wm + i * 16 + lrow) * 32 + lq * 8);
    #pragma unroll
    for (int j = 0; j < 4; ++j)
      bf[j] = *(const h8*)(Bs + (wn + j * 16 + lrow) * 32 + lq * 8);
    #pragma unroll
    for (int i = 0; i < 4; ++i)
      #pragma unroll
      for (int j = 0; j < 4; ++j)
        acc[i][j] = __builtin_amdgcn_mfma_f32_16x16x32_f16(af[i], bf[j], acc[i][j], 0, 0, 0);
  }

  #pragma unroll
  for (int i = 0; i < 4; ++i) {
    #pragma unroll
    for (int r = 0; r < 4; ++r) {
      const int m = bm + wm + i * 16 + lq * 4 + r;
      if (m < Mstore) {
        const float rsc = row_scale ? row_scale[m] : 1.0f;
        OutT* crow = C + (size_t)m * Nc + bn + wn + lrow;
        #pragma unroll
        for (int j = 0; j < 4; ++j) {
          float v = acc[i][j][r] * rsc;
          if (bias) v += bias[bn + wn + j * 16 + lrow];
          crow[j * 16] = (OutT)v;
        }
      }
    }
  }
}

// ---------------- CSR aggregation, fp16 gather / fp32 accumulate ----------------
// out[n] = relu(((sum_{e:dst=n} Z[csr[e]]) (+ Z[n] if SELF)) * out_scale[n] + bias)
// 16 lanes per node; 16B gathers. R1: 4 edges in flight per iteration (12/8/4
// outstanding global_load_dwordx4 per lane-group) to break the per-edge
// vmcnt(0) serialization that made the old version latency-bound.

template <int D>
__device__ __forceinline__ void acc_edges4(
    float (*acc)[8], const _Float16* __restrict__ Z, int lane,
    int s0, int s1, int s2, int s3, int k) {
  constexpr int NV = D / 128;  // h8 chunks per lane (3/2/1)
  const h8* z0 = (const h8*)(Z + (size_t)s0 * D) + lane;
  const h8* z1 = (const h8*)(Z + (size_t)s1 * D) + lane;
  const h8* z2 = (const h8*)(Z + (size_t)s2 * D) + lane;
  const h8* z3 = (const h8*)(Z + (size_t)s3 * D) + lane;
  h8 t0[NV], t1[NV], t2[NV], t3[NV];
  #pragma unroll
  for (int v = 0; v < NV; ++v) t0[v] = z0[v * 16];
  #pragma unroll
  for (int v = 0; v < NV; ++v) t1[v] = z1[v * 16];
  #pragma unroll
  for (int v = 0; v < NV; ++v) t2[v] = z2[v * 16];
  #pragma unroll
  for (int v = 0; v < NV; ++v) t3[v] = z3[v * 16];
  #pragma unroll
  for (int v = 0; v < NV; ++v)
    #pragma unroll
    for (int q = 0; q < 8; ++q) acc[v][q] += (float)t0[v][q];
  if (k > 1) {
    #pragma unroll
    for (int v = 0; v < NV; ++v)
      #pragma unroll
      for (int q = 0; q < 8; ++q) acc[v][q] += (float)t1[v][q];
  }
  if (k > 2) {
    #pragma unroll
    for (int v = 0; v < NV; ++v)
      #pragma unroll
      for (int q = 0; q < 8; ++q) acc[v][q] += (float)t2[v][q];
  }
  if (k > 3) {
    #pragma unroll
    for (int v = 0; v < NV; ++v)
      #pragma unroll
      for (int q = 0; q < 8; ++q) acc[v][q] += (float)t3[v][q];
  }
}

template <int D, bool SELF>
__global__ __launch_bounds__(256) void agg_h(
    const _Float16* __restrict__ Z, const int* __restrict__ row_ptr,
    const int* __restrict__ csr, const float* __restrict__ out_scale,
    const float* __restrict__ bias, _Float16* __restrict__ out, int n) {
  constexpr int NV = D / 128;
  const int gid = threadIdx.x >> 4;
  const int lane = threadIdx.x & 15;
  const int node = blockIdx.x * 16 + gid;
  if (node >= n) return;

  const int rs = row_ptr[node], re = row_ptr[node + 1];

  float acc[NV][8];
  #pragma unroll
  for (int v = 0; v < NV; ++v)
    #pragma unroll
    for (int q = 0; q < 8; ++q) acc[v][q] = 0.f;

  for (int e = rs; e < re; e += 16) {
    int m = re - e; if (m > 16) m = 16;
    const int eid = (lane < m) ? csr[e + lane] : 0;
    #pragma unroll 1
    for (int j = 0; j < m; j += 4) {
      // clamp indices into the valid range; duplicate loads are cache hits
      // and their accumulates are suppressed by the k-guards.
      const int i1 = (j + 1 < m) ? j + 1 : m - 1;
      const int i2 = (j + 2 < m) ? j + 2 : m - 1;
      const int i3 = (j + 3 < m) ? j + 3 : m - 1;
      const int s0 = __shfl(eid, j, 16);
      const int s1 = __shfl(eid, i1, 16);
      const int s2 = __shfl(eid, i2, 16);
      const int s3 = __shfl(eid, i3, 16);
      acc_edges4<D>(acc, Z, lane, s0, s1, s2, s3, m - j);
    }
  }

  const float osc = out_scale[node];
  const h8* zs = (const h8*)(Z + (size_t)node * D);
  _Float16* orow = out + (size_t)node * D;
  #pragma unroll
  for (int v = 0; v < NV; ++v) {
    const int idx = lane + v * 16;
    if (SELF) {
      h8 t = zs[idx];
      #pragma unroll
      for (int q = 0; q < 8; ++q) acc[v][q] += (float)t[q];
    }
    h8 r;
    #pragma unroll
    for (int q = 0; q < 8; ++q) {
      float x = acc[v][q] * osc + bias[idx * 8 + q];
      r[q] = (_Float16)fmaxf(x, 0.f);
    }
    *(h8*)(orow + idx * 8) = r;
  }
}

// ---------------- host-side orchestration ----------------

static void launch_cvt(const float* in, _Float16* out, long n_in, long n_pad,
                       hipStream_t st) {
  long thr = n_pad / 4;
  cvt_kernel<<<(int)((thr + 255) / 256), 256, 0, st>>>(in, out, n_in, n_pad);
}

extern "C" void kernel_launch(void* const* d_in, const int* in_sizes, int n_in,
                              void* d_out, int out_size, void* d_ws, size_t ws_size,
                              hipStream_t stream) {
  const float* features = (const float*)d_in[0];
  const int*   src      = (const int*)d_in[1];
  const int*   dst      = (const int*)d_in[2];
  const float* wsrc[7] = {(const float*)d_in[3],  (const float*)d_in[5],
                          (const float*)d_in[7],  (const float*)d_in[9],
                          (const float*)d_in[11], (const float*)d_in[13],
                          (const float*)d_in[15]};  // sw0,gw0,sw1,gw1,sw2,gw2,fc
  const float* sb[3] = {(const float*)d_in[4],  (const float*)d_in[8],  (const float*)d_in[12]};
  const float* gb[3] = {(const float*)d_in[6],  (const float*)d_in[10], (const float*)d_in[14]};
  const float* fc_b  = (const float*)d_in[16];

  const int N = in_sizes[0] / 512;
  const int E = in_sizes[1];
  const int MB = (N + 127) / 128;
  const int Mpad = MB * 128;

  const int wcnt[7] = {384 * 512, 384 * 384, 256 * 384, 256 * 256,
                       128 * 256, 128 * 128, 128 * 128};

  // workspace layout (fp16 buffers first, 16B-aligned throughout)
  char* ws = (char*)d_ws;
  _Float16* featH = (_Float16*)ws;                       // Mpad*512
  _Float16* hA    = featH + (size_t)Mpad * 512;          // Mpad*384 (activations)
  _Float16* hB    = hA + (size_t)Mpad * 384;             // Mpad*384 (Z)
  _Float16* wH[7];
  {
    _Float16* p = hB + (size_t)Mpad * 384;
    for (int i = 0; i < 7; ++i) { wH[i] = p; p += wcnt[i]; }
  }
  int* csr     = (int*)(wH[6] + wcnt[6]);                // E ints
  int* rp      = csr + E;                                // N+1
  int* in_dg   = rp + (N + 1);                           // N (zeroed)
  int* out_dg  = in_dg + N;                              // N (zeroed)
  int* cnt     = out_dg + N;                             // N (zeroed)
  float* inv_src = (float*)(cnt + N);                    // N
  float* inv_dst = inv_src + N;                          // N
  float* inv_den = inv_dst + N;                          // N

  size_t totw = 0; for (int i = 0; i < 7; ++i) totw += wcnt[i];
  size_t needed = ((size_t)Mpad * (512 + 384 + 384) + totw) * 2 +
                  ((size_t)E + (N + 1) + 6 * (size_t)N) * 4;
  if (ws_size < needed) return;

  (void)hipMemsetAsync(in_dg, 0, sizeof(int) * 3 * (size_t)N, stream);

  const int eb = (E + 255) / 256;
  const int nb = (N + 255) / 256;
  deg_kernel<<<eb, 256, 0, stream>>>(src, dst, in_dg, out_dg, E);
  scan_kernel<<<1, 1024, 0, stream>>>(in_dg, rp, N);
  scatter_kernel<<<eb, 256, 0, stream>>>(src, dst, rp, cnt, csr, E);
  scaler_kernel<<<nb, 256, 0, stream>>>(in_dg, out_dg, inv_src, inv_dst, inv_den, N);

  // conversions
  launch_cvt(features, featH, (long)N * 512, (long)Mpad * 512, stream);
  for (int i = 0; i < 7; ++i) launch_cvt(wsrc[i], wH[i], wcnt[i], wcnt[i], stream);

  const int dout[3] = {384, 256, 128};
  const _Float16* h = featH;
  int K = 512;
  for (int s = 0; s < 3; ++s) {
    const int D = dout[s];
    dim3 gg(MB, D / 128);
    const int ab = (N + 15) / 16;
    // SAGE: Z = h @ sw^T ; h' = relu((sum_in Z + Z_self)*inv_den + sb)
    hgemm<_Float16><<<gg, 256, 0, stream>>>(h, wH[2 * s], hB, Mpad, K, D, nullptr, nullptr);
    if (D == 384)      agg_h<384, true><<<ab, 256, 0, stream>>>(hB, rp, csr, inv_den, sb[s], hA, N);
    else if (D == 256) agg_h<256, true><<<ab, 256, 0, stream>>>(hB, rp, csr, inv_den, sb[s], hA, N);
    else               agg_h<128, true><<<ab, 256, 0, stream>>>(hB, rp, csr, inv_den, sb[s], hA, N);
    // GraphConv: Z = (h'*inv_src) @ gw^T ; h'' = relu((sum_in Z)*inv_dst + gb)
    hgemm<_Float16><<<gg, 256, 0, stream>>>(hA, wH[2 * s + 1], hB, Mpad, D, D, inv_src, nullptr);
    if (D == 384)      agg_h<384, false><<<ab, 256, 0, stream>>>(hB, rp, csr, inv_dst, gb[s], hA, N);
    else if (D == 256) agg_h<256, false><<<ab, 256, 0, stream>>>(hB, rp, csr, inv_dst, gb[s], hA, N);
    else               agg_h<128, false><<<ab, 256, 0, stream>>>(hB, rp, csr, inv_dst, gb[s], hA, N);
    h = hA;
    K = D;
  }
  // final FC: fp32 out + bias, no relu
  dim3 gf(MB, 1);
  hgemm<float><<<gf, 256, 0, stream>>>(h, wH[6], (float*)d_out, N, 128, 128, nullptr, fc_b);
}